// Round 1
// baseline (26608.643 us; speedup 1.0000x reference)
//
#include <hip/hip_runtime.h>
#include <hip/hip_cooperative_groups.h>

#define B_ 64
#define H_ 1024
#define IN_ 512
#define S_ 256
#define L_ 6
#define NG_ 4096
#define NWG 256
#define NTICK (S_ + L_ - 1)

typedef __bf16 bf16x8 __attribute__((ext_vector_type(8)));
typedef float f32x4 __attribute__((ext_vector_type(4)));
typedef unsigned short ushort4v __attribute__((ext_vector_type(4)));

// weight offsets in elements (bf16) inside ws
// U0t: 4096x512, V0t: 4096x1024, then per layer l>=1: Ut 4096x1024, Vt 4096x1024
#define OFF_U0 0ul
#define OFF_V0 2097152ul
#define OFF_UL(l) (6291456ul + (unsigned long)((l) - 1) * 8388608ul)
#define OFF_VL(l) (OFF_UL(l) + 4194304ul)
#define WT_BYTES 96468992ul   // 48,234,496 elems * 2
#define XB_BYTES 16777216ul   // 8,388,608 elems * 2
#define HBF_ELEMS 786432ul    // 2*L*B*H

__device__ __forceinline__ unsigned short f2bf(float f) {
  union { float f; unsigned u; } v; v.f = f;
  unsigned r = v.u + 0x7fffu + ((v.u >> 16) & 1u);
  return (unsigned short)(r >> 16);
}

// ---- one-time weight transpose + bf16 convert: Wt[n][k] = bf16(W[k][n]) ----
__global__ void k_transpose_bf16(const float* __restrict__ W,
                                 unsigned short* __restrict__ Wt,
                                 int K, int N) {
  __shared__ float tile[32][33];
  int n0 = blockIdx.x * 32, k0 = blockIdx.y * 32;
  int tx = threadIdx.x, ty = threadIdx.y; // 32 x 8
#pragma unroll
  for (int i = 0; i < 32; i += 8)
    tile[ty + i][tx] = W[(size_t)(k0 + ty + i) * N + (n0 + tx)];
  __syncthreads();
#pragma unroll
  for (int i = 0; i < 32; i += 8)
    Wt[(size_t)(n0 + ty + i) * K + (k0 + tx)] = f2bf(tile[tx][ty + i]);
}

// ---- one-time x -> bf16 ----
__global__ void k_cvt_bf16(const float* __restrict__ src,
                           unsigned short* __restrict__ dst, int n4) {
  int i = blockIdx.x * blockDim.x + threadIdx.x;
  if (i < n4) {
    float4 v = ((const float4*)src)[i];
    ushort4v o = { f2bf(v.x), f2bf(v.y), f2bf(v.z), f2bf(v.w) };
    ((ushort4v*)dst)[i] = o;
  }
}

// K-loop: acc[mf] += A[mf*16+..][k..] * B[k..][n..]
__device__ __forceinline__ void gemm_acc(f32x4 acc[4],
                                         const unsigned short* __restrict__ Arow,
                                         size_t strideA,
                                         const unsigned short* __restrict__ Brow,
                                         int K) {
  const size_t s16 = 16 * strideA;
  const unsigned short* r0 = Arow;
  const unsigned short* r1 = Arow + s16;
  const unsigned short* r2 = Arow + 2 * s16;
  const unsigned short* r3 = Arow + 3 * s16;
#pragma unroll 4
  for (int k = 0; k < K; k += 32) {
    bf16x8 bv = *(const bf16x8*)(Brow + k);
    bf16x8 a0 = *(const bf16x8*)(r0 + k);
    bf16x8 a1 = *(const bf16x8*)(r1 + k);
    bf16x8 a2 = *(const bf16x8*)(r2 + k);
    bf16x8 a3 = *(const bf16x8*)(r3 + k);
    acc[0] = __builtin_amdgcn_mfma_f32_16x16x32_bf16(a0, bv, acc[0], 0, 0, 0);
    acc[1] = __builtin_amdgcn_mfma_f32_16x16x32_bf16(a1, bv, acc[1], 0, 0, 0);
    acc[2] = __builtin_amdgcn_mfma_f32_16x16x32_bf16(a2, bv, acc[2], 0, 0, 0);
    acc[3] = __builtin_amdgcn_mfma_f32_16x16x32_bf16(a3, bv, acc[3], 0, 0, 0);
  }
}

__global__ void __launch_bounds__(256)
k_lstm(const unsigned short* __restrict__ xb,
       const unsigned short* __restrict__ Wt,
       const float* __restrict__ b0,
       const float* __restrict__ bL,
       unsigned short* __restrict__ hbf,   // [2][L][B][H] bf16, pre-zeroed
       float* __restrict__ out) {
  cooperative_groups::grid_group grid = cooperative_groups::this_grid();
  float* __restrict__ seq = out;                           // [B][S][H]
  float* __restrict__ hf = out + (size_t)B_ * S_ * H_;     // [L][B][H]
  float* __restrict__ cf = hf + (size_t)L_ * B_ * H_;      // [L][B][H]
  __shared__ float zs[4][64][16];

  const int tid = threadIdx.x;
  const int wave = tid >> 6;
  const int lane = tid & 63;
  const int l15 = lane & 15;
  const int kg = lane >> 4;
  const int wg = blockIdx.x;

  for (int T = 0; T < NTICK; ++T) {
    const int lmin = (T > S_ - 1) ? (T - (S_ - 1)) : 0;
    const int lmax = (T < L_ - 1) ? T : (L_ - 1);
    const int ntask = (lmax - lmin + 1) << 6;
    const unsigned short* __restrict__ hprev =
        hbf + (size_t)((T + 1) & 1) * (L_ * B_ * H_);
    unsigned short* __restrict__ hcur =
        hbf + (size_t)(T & 1) * (L_ * B_ * H_);

    for (int task = wg; task < ntask; task += NWG) {
      const int l = lmin + (task >> 6);
      const int jb = task & 63;
      const int t = T - l;
      const int jcol0 = jb << 4;
      const int ngl = (wave << 10) + jcol0 + l15; // weight row (output col)

      const unsigned short* A1;
      size_t sA1;
      const unsigned short* WU;
      int K1;
      if (l == 0) {
        A1 = xb + (size_t)t * IN_;  // row b at + b*S*IN
        sA1 = (size_t)S_ * IN_;
        WU = Wt + OFF_U0;
        K1 = IN_;
      } else {
        A1 = hprev + (size_t)(l - 1) * (B_ * H_);
        sA1 = H_;
        WU = Wt + OFF_UL(l);
        K1 = H_;
      }
      const unsigned short* A2 = hprev + (size_t)l * (B_ * H_);
      const unsigned short* WV = Wt + ((l == 0) ? OFF_V0 : OFF_VL(l));

      f32x4 acc[4];
#pragma unroll
      for (int i = 0; i < 4; ++i) acc[i] = (f32x4){0.f, 0.f, 0.f, 0.f};

      gemm_acc(acc, A1 + (size_t)l15 * sA1 + kg * 8, sA1,
               WU + (size_t)ngl * K1 + kg * 8, K1);
      gemm_acc(acc, A2 + (size_t)l15 * H_ + kg * 8, H_,
               WV + (size_t)ngl * H_ + kg * 8, H_);

      // D layout: col = lane&15, row = (lane>>4)*4 + j
#pragma unroll
      for (int mf = 0; mf < 4; ++mf)
#pragma unroll
        for (int j = 0; j < 4; ++j)
          zs[wave][mf * 16 + kg * 4 + j][l15] = acc[mf][j];
      __syncthreads();

      // ---- gate phase: 256 threads cover 64 rows x 16 cols, 4 each ----
      {
        const float* __restrict__ bias = (l == 0) ? b0 : (bL + (size_t)(l - 1) * NG_);
        const int m = tid >> 2;            // batch row
        const int nq = (tid & 3) << 2;     // col within 16
        const int col = jcol0 + nq;        // col within H
        f32x4 zi = *(const f32x4*)&zs[0][m][nq] + *(const f32x4*)(bias + col);
        f32x4 zf = *(const f32x4*)&zs[1][m][nq] + *(const f32x4*)(bias + 1024 + col);
        f32x4 zg = *(const f32x4*)&zs[2][m][nq] + *(const f32x4*)(bias + 2048 + col);
        f32x4 zo = *(const f32x4*)&zs[3][m][nq] + *(const f32x4*)(bias + 3072 + col);
        const size_t cbase = ((size_t)l * B_ + m) * H_ + col;
        f32x4 cold;
        if (t == 0) cold = (f32x4){0.f, 0.f, 0.f, 0.f};
        else cold = *(const f32x4*)(cf + cbase);
        f32x4 cnew, hv;
#pragma unroll
        for (int j = 0; j < 4; ++j) {
          float iv = 1.f / (1.f + expf(-zi[j]));
          float fv = 1.f / (1.f + expf(-zf[j]));
          float gv = tanhf(zg[j]);
          float ov = 1.f / (1.f + expf(-zo[j]));
          float cn = fv * cold[j] + iv * gv;
          cnew[j] = cn;
          hv[j] = ov * tanhf(cn);
        }
        *(f32x4*)(cf + cbase) = cnew;
        *(f32x4*)(hf + cbase) = hv;
        ushort4v hb4 = { f2bf(hv[0]), f2bf(hv[1]), f2bf(hv[2]), f2bf(hv[3]) };
        *(ushort4v*)(hcur + (size_t)l * (B_ * H_) + (size_t)m * H_ + col) = hb4;
        if (l == L_ - 1)
          *(f32x4*)(seq + ((size_t)m * S_ + t) * H_ + col) = hv;
      }
      __syncthreads(); // protect zs before next task reuses it
    }
    grid.sync();
  }
}

extern "C" void kernel_launch(void* const* d_in, const int* in_sizes, int n_in,
                              void* d_out, int out_size, void* d_ws, size_t ws_size,
                              hipStream_t stream) {
  const float* x = (const float*)d_in[0];
  const float* U0 = (const float*)d_in[1];
  const float* V0 = (const float*)d_in[2];
  const float* b0 = (const float*)d_in[3];
  const float* U = (const float*)d_in[4];
  const float* V = (const float*)d_in[5];
  const float* bL = (const float*)d_in[6];
  float* out = (float*)d_out;

  char* ws = (char*)d_ws;
  unsigned short* Wt = (unsigned short*)ws;
  unsigned short* xb = (unsigned short*)(ws + WT_BYTES);
  unsigned short* hbf = (unsigned short*)(ws + WT_BYTES + XB_BYTES);

  dim3 tb(32, 8);
  hipLaunchKernelGGL(k_transpose_bf16, dim3(128, 16), tb, 0, stream, U0, Wt + OFF_U0, 512, 4096);
  hipLaunchKernelGGL(k_transpose_bf16, dim3(128, 32), tb, 0, stream, V0, Wt + OFF_V0, 1024, 4096);
  for (int l = 1; l < 6; ++l) {
    hipLaunchKernelGGL(k_transpose_bf16, dim3(128, 32), tb, 0, stream,
                       U + (size_t)(l - 1) * 4194304ul, Wt + OFF_UL(l), 1024, 4096);
    hipLaunchKernelGGL(k_transpose_bf16, dim3(128, 32), tb, 0, stream,
                       V + (size_t)(l - 1) * 4194304ul, Wt + OFF_VL(l), 1024, 4096);
  }
  int n4 = (B_ * S_ * IN_) / 4;
  hipLaunchKernelGGL(k_cvt_bf16, dim3((n4 + 255) / 256), dim3(256), 0, stream, x, xb, n4);
  hipMemsetAsync(hbf, 0, HBF_ELEMS * 2, stream);

  void* args[] = { (void*)&xb, (void*)&Wt, (void*)&b0, (void*)&bL, (void*)&hbf, (void*)&out };
  hipLaunchCooperativeKernel((void*)k_lstm, dim3(NWG), dim3(256), args, 0, stream);
}